// Round 1
// 28199.963 us; speedup vs baseline: 1.8202x; 1.8202x over previous
//
#include <hip/hip_runtime.h>
#include <hip/hip_fp16.h>

#define P_LEN 1000
#define Q_LEN 100
#define BATCH 128
#define D_IN 512
#define HID 256

#define NGROUP 4
#define WPG 32   // workgroups per group
#define BPG 32   // batches per group
#define NTHR 256

typedef _Float16 f16x8 __attribute__((ext_vector_type(8)));
typedef _Float16 f16x2 __attribute__((ext_vector_type(2)));
typedef float f32x4 __attribute__((ext_vector_type(4)));
typedef float f32x2 __attribute__((ext_vector_type(2)));

#define LOG2E 1.4426950408889634f

__device__ __forceinline__ float fexp2(float x) {
#if __has_builtin(__builtin_amdgcn_exp2f)
  return __builtin_amdgcn_exp2f(x);
#else
  return exp2f(x);
#endif
}
__device__ __forceinline__ float frcp(float x) {
#if __has_builtin(__builtin_amdgcn_rcpf)
  return __builtin_amdgcn_rcpf(x);
#else
  return 1.0f / x;
#endif
}
__device__ __forceinline__ float fast_tanh(float x) {
  float t = fexp2(x * (2.0f * LOG2E));
  return (t - 1.0f) * frcp(t + 1.0f);
}
__device__ __forceinline__ float fast_sigmoid(float x) {
  return frcp(1.0f + fexp2(-x * LOG2E));
}

// ---------------------------------------------------------------- coherent (LLC) access
// All cross-WG exchange traffic bypasses L1/L2 (sc0 sc1) and is serviced at the
// Infinity Cache = device coherence point. No buffer_wbl2/buffer_inv fences needed,
// so Qp/Pp/weights stay L2-resident across the whole scan.

__device__ __forceinline__ void st_f32_sys(float* p, float v) {
  asm volatile("global_store_dword %0, %1, off sc0 sc1" :: "v"(p), "v"(v) : "memory");
}
__device__ __forceinline__ void st2f_sys(float* p, f32x2 v) {
  asm volatile("global_store_dwordx2 %0, %1, off sc0 sc1" :: "v"(p), "v"(v) : "memory");
}
__device__ __forceinline__ void st_u32_sys(unsigned* p, unsigned v) {
  asm volatile("global_store_dword %0, %1, off sc0 sc1" :: "v"(p), "v"(v) : "memory");
}
__device__ __forceinline__ void st_h16_sys(__half* p, __half v) {
  unsigned u = (unsigned)__half_as_ushort(v);
  asm volatile("global_store_short %0, %1, off sc0 sc1" :: "v"(p), "v"(u) : "memory");
}

__device__ __forceinline__ float4 ldx4_sys(const float* p) {
  f32x4 v;
  asm volatile("global_load_dwordx4 %0, %1, off sc0 sc1\n\t"
               "s_waitcnt vmcnt(0)"
               : "=&v"(v) : "v"(p) : "memory");
  return make_float4(v.x, v.y, v.z, v.w);
}

__device__ __forceinline__ float4 ld4f_sys(const float* p0, const float* p1,
                                           const float* p2, const float* p3) {
  float a, b, c, d;
  asm volatile(
      "global_load_dword %0, %4, off sc0 sc1\n\t"
      "global_load_dword %1, %5, off sc0 sc1\n\t"
      "global_load_dword %2, %6, off sc0 sc1\n\t"
      "global_load_dword %3, %7, off sc0 sc1\n\t"
      "s_waitcnt vmcnt(0)"
      : "=&v"(a), "=&v"(b), "=&v"(c), "=&v"(d)
      : "v"(p0), "v"(p1), "v"(p2), "v"(p3)
      : "memory");
  return make_float4(a, b, c, d);
}

// 8 x 16B from one row (stride 64B), single LLC latency.
__device__ __forceinline__ void ld8h_sys(const __half* p,
    f16x8& o0, f16x8& o1, f16x8& o2, f16x8& o3,
    f16x8& o4, f16x8& o5, f16x8& o6, f16x8& o7) {
  asm volatile(
      "global_load_dwordx4 %0, %8, off sc0 sc1\n\t"
      "global_load_dwordx4 %1, %8, off offset:64 sc0 sc1\n\t"
      "global_load_dwordx4 %2, %8, off offset:128 sc0 sc1\n\t"
      "global_load_dwordx4 %3, %8, off offset:192 sc0 sc1\n\t"
      "global_load_dwordx4 %4, %8, off offset:256 sc0 sc1\n\t"
      "global_load_dwordx4 %5, %8, off offset:320 sc0 sc1\n\t"
      "global_load_dwordx4 %6, %8, off offset:384 sc0 sc1\n\t"
      "global_load_dwordx4 %7, %8, off offset:448 sc0 sc1\n\t"
      "s_waitcnt vmcnt(0)"
      : "=&v"(o0), "=&v"(o1), "=&v"(o2), "=&v"(o3),
        "=&v"(o4), "=&v"(o5), "=&v"(o6), "=&v"(o7)
      : "v"(p)
      : "memory");
}

// 16 x 16B from one row (stride 64B), single LLC latency.
__device__ __forceinline__ void ld16h_sys(const __half* p,
    f16x8& o0, f16x8& o1, f16x8& o2, f16x8& o3,
    f16x8& o4, f16x8& o5, f16x8& o6, f16x8& o7,
    f16x8& o8, f16x8& o9, f16x8& o10, f16x8& o11,
    f16x8& o12, f16x8& o13, f16x8& o14, f16x8& o15) {
  asm volatile(
      "global_load_dwordx4 %0, %16, off sc0 sc1\n\t"
      "global_load_dwordx4 %1, %16, off offset:64 sc0 sc1\n\t"
      "global_load_dwordx4 %2, %16, off offset:128 sc0 sc1\n\t"
      "global_load_dwordx4 %3, %16, off offset:192 sc0 sc1\n\t"
      "global_load_dwordx4 %4, %16, off offset:256 sc0 sc1\n\t"
      "global_load_dwordx4 %5, %16, off offset:320 sc0 sc1\n\t"
      "global_load_dwordx4 %6, %16, off offset:384 sc0 sc1\n\t"
      "global_load_dwordx4 %7, %16, off offset:448 sc0 sc1\n\t"
      "global_load_dwordx4 %8, %16, off offset:512 sc0 sc1\n\t"
      "global_load_dwordx4 %9, %16, off offset:576 sc0 sc1\n\t"
      "global_load_dwordx4 %10, %16, off offset:640 sc0 sc1\n\t"
      "global_load_dwordx4 %11, %16, off offset:704 sc0 sc1\n\t"
      "global_load_dwordx4 %12, %16, off offset:768 sc0 sc1\n\t"
      "global_load_dwordx4 %13, %16, off offset:832 sc0 sc1\n\t"
      "global_load_dwordx4 %14, %16, off offset:896 sc0 sc1\n\t"
      "global_load_dwordx4 %15, %16, off offset:960 sc0 sc1\n\t"
      "s_waitcnt vmcnt(0)"
      : "=&v"(o0), "=&v"(o1), "=&v"(o2), "=&v"(o3),
        "=&v"(o4), "=&v"(o5), "=&v"(o6), "=&v"(o7),
        "=&v"(o8), "=&v"(o9), "=&v"(o10), "=&v"(o11),
        "=&v"(o12), "=&v"(o13), "=&v"(o14), "=&v"(o15)
      : "v"(p)
      : "memory");
}

// ---------------------------------------------------------------- convert
__global__ void cvt_f32_f16(const float* __restrict__ src, __half* __restrict__ dst, int n) {
  int i = blockIdx.x * blockDim.x + threadIdx.x;
  int stride = gridDim.x * blockDim.x;
  for (; i < n; i += stride) dst[i] = __float2half(src[i]);
}

// ---------------------------------------------------------------- GEMM (precompute Qp/Pp)
#define BM 128
#define BN 64
#define BK 32
__global__ __launch_bounds__(256) void gemm_a32w16(const float* __restrict__ A,
                                                   const __half* __restrict__ W,
                                                   __half* __restrict__ C,
                                                   int M, int N, int K) {
  __shared__ __align__(16) __half As[BM][BK + 8];
  __shared__ __align__(16) __half Bs[BN][BK + 8];
  int t = threadIdx.x;
  int lane = t & 63, wave = t >> 6;
  int wm = wave >> 1, wn = wave & 1;
  int bm = blockIdx.x * BM, bn = blockIdx.y * BN;
  f32x4 acc[4][2] = {};
  int fr = lane & 15, fk = (lane >> 4) * 8, fq = lane >> 4;

  for (int kk = 0; kk < K; kk += BK) {
    {
      int r = t >> 1, c0 = (t & 1) * 16;
      const float* ap = A + (long)(bm + r) * K + kk + c0;
      float4 f0 = ((const float4*)ap)[0];
      float4 f1 = ((const float4*)ap)[1];
      float4 f2 = ((const float4*)ap)[2];
      float4 f3 = ((const float4*)ap)[3];
      __half2* dp = (__half2*)&As[r][c0];
      dp[0] = __float22half2_rn(make_float2(f0.x, f0.y));
      dp[1] = __float22half2_rn(make_float2(f0.z, f0.w));
      dp[2] = __float22half2_rn(make_float2(f1.x, f1.y));
      dp[3] = __float22half2_rn(make_float2(f1.z, f1.w));
      dp[4] = __float22half2_rn(make_float2(f2.x, f2.y));
      dp[5] = __float22half2_rn(make_float2(f2.z, f2.w));
      dp[6] = __float22half2_rn(make_float2(f3.x, f3.y));
      dp[7] = __float22half2_rn(make_float2(f3.z, f3.w));
    }
    {
      int r = t >> 2, c0 = (t & 3) * 8;
      uint4 w = *(const uint4*)(W + (long)(bn + r) * K + kk + c0);
      *(uint4*)&Bs[r][c0] = w;
    }
    __syncthreads();
    f16x8 af[4], bf[2];
#pragma unroll
    for (int i = 0; i < 4; i++) af[i] = *(const f16x8*)&As[wm * 64 + i * 16 + fr][fk];
#pragma unroll
    for (int j = 0; j < 2; j++) bf[j] = *(const f16x8*)&Bs[wn * 32 + j * 16 + fr][fk];
#pragma unroll
    for (int i = 0; i < 4; i++)
#pragma unroll
      for (int j = 0; j < 2; j++)
        acc[i][j] = __builtin_amdgcn_mfma_f32_16x16x32_f16(af[i], bf[j], acc[i][j], 0, 0, 0);
    __syncthreads();
  }
#pragma unroll
  for (int i = 0; i < 4; i++)
#pragma unroll
    for (int j = 0; j < 2; j++)
#pragma unroll
      for (int r = 0; r < 4; r++) {
        int row = bm + wm * 64 + i * 16 + fq * 4 + r;
        int col = bn + wn * 32 + j * 16 + fr;
        C[(long)row * N + col] = __float2half(acc[i][j][r]);
      }
}

// ---------------------------------------------------------------- group barrier
// Lightweight: all exchange data was stored with sc0/sc1 (at LLC once vmcnt
// drains), so the barrier needs NO cache writeback/invalidate. Each wave drains
// its own stores, then one relaxed agent-scope atomic per WG.
__device__ __forceinline__ void group_barrier(unsigned* cnt, unsigned target) {
  asm volatile("s_waitcnt vmcnt(0)" ::: "memory");
  __syncthreads();
  if (threadIdx.x == 0) {
    __hip_atomic_fetch_add(cnt, 1u, __ATOMIC_RELAXED, __HIP_MEMORY_SCOPE_AGENT);
    while (__hip_atomic_load(cnt, __ATOMIC_RELAXED, __HIP_MEMORY_SCOPE_AGENT) < target) {
      __builtin_amdgcn_s_sleep(1);
    }
  }
  __syncthreads();
}

// ---------------------------------------------------------------- cooperative scan
__global__ __launch_bounds__(256) void scan_coop(
    const __half* __restrict__ Pp, const __half* __restrict__ Qp,
    const __half* __restrict__ WvP, const __half* __restrict__ Whh,
    const __half* __restrict__ Wg, const __half* __restrict__ Wih,
    const float* __restrict__ vT, float* __restrict__ out,
    float* __restrict__ Y1b,   // [G][32][1024] f32: cols 0..255 lh, 256.. hh(r,z,n)
    float* __restrict__ uFb,   // [G][32][512]  f32 utct
    __half* __restrict__ uHb,  // [G][32][512]  f16 utct
    __half* __restrict__ xHb,  // [G][32][512]  f16 x
    float* __restrict__ pFb,   // [G][32][256]  f32 prev
    __half* __restrict__ pHb,  // [G][32][256]  f16 prev
    unsigned* __restrict__ bars)  // [G][64] counters (1 line/group)
{
  const int bid = blockIdx.x;
  const int g = bid >> 5;
  const int w = bid & 31;
  const int t = threadIdx.x;
  const int lane = t & 63, wave = t >> 6;
  const int fr = lane & 15, fq = lane >> 4;
  const int fk = fq * 8;

  float* Y1 = Y1b + (size_t)g * BPG * 1024;
  float* uF = uFb + (size_t)g * BPG * 512;
  __half* uH = uHb + (size_t)g * BPG * 512;
  __half* xH = xHb + (size_t)g * BPG * 512;
  float* pF = pFb + (size_t)g * BPG * 256;
  __half* pH = pHb + (size_t)g * BPG * 256;
  unsigned* cnt = bars + g * 64;

  __shared__ __align__(16) __half sW1[32][256];   // slots: 0..7 WvP rows w*8+s; 8..31 Whh gate rows
  __shared__ __align__(16) __half sWg[16][512];   // Wg rows w*16+s
  __shared__ __align__(16) __half sW3[24][512];   // Wih gate rows (8 per gate at jj=w*8..)
  __shared__ __align__(16) float scratch[1024];   // phase2 ct partials / gemm3 xg staging
  __shared__ float s_logits[Q_LEN];
  __shared__ float s_a[Q_LEN];

  // ---- load resident weight slices (normal cached loads; read-once)
  for (int i = t; i < 32 * 32; i += NTHR) {       // sW1: 32 slots x 32 uint4
    int slot = i >> 5, off = (i & 31) * 8;
    const __half* src;
    if (slot < 8) src = WvP + (size_t)(w * 8 + slot) * 256;
    else {
      int gate = (slot - 8) >> 3, jl = (slot - 8) & 7;
      src = Whh + (size_t)(gate * 256 + w * 8 + jl) * 256;
    }
    *(uint4*)&sW1[slot][off] = *(const uint4*)(src + off);
  }
  for (int i = t; i < 16 * 64; i += NTHR) {       // sWg
    int s = i >> 6, off = (i & 63) * 8;
    *(uint4*)&sWg[s][off] = *(const uint4*)(Wg + (size_t)(w * 16 + s) * 512 + off);
  }
  for (int i = t; i < 24 * 64; i += NTHR) {       // sW3
    int s = i >> 6, off = (i & 63) * 8;
    int gate = s >> 3, jl = s & 7;
    *(uint4*)&sW3[s][off] = *(const uint4*)(Wih + (size_t)(gate * 256 + w * 8 + jl) * 512 + off);
  }

  const int bg_att = g * BPG + w;   // this WG's batch for the attention phase
  const int h0 = lane * 4;
  float vt0 = vT[h0], vt1 = vT[h0 + 1], vt2 = vT[h0 + 2], vt3 = vT[h0 + 3];
  __syncthreads();

  unsigned target = 0;

  for (int p = 0; p < P_LEN; ++p) {
    // ---------------- GEMM1: Y1[b][col] = [WvP;Whh] @ prev   (M=32,N=32,K=256)
    {
      const int mt = wave >> 1, nt = wave & 1;
      const __half* arow = pH + (mt * 16 + fr) * 256 + fk;
      f16x8 af[8];
      ld8h_sys(arow, af[0], af[1], af[2], af[3], af[4], af[5], af[6], af[7]);
      f32x4 acc = {0.f, 0.f, 0.f, 0.f};
#pragma unroll
      for (int kc = 0; kc < 8; ++kc) {
        f16x8 bf = *(const f16x8*)&sW1[nt * 16 + fr][kc * 32 + fk];
        acc = __builtin_amdgcn_mfma_f32_16x16x32_f16(af[kc], bf, acc, 0, 0, 0);
      }
      int slot = nt * 16 + fr;
      int col = (slot < 8) ? (w * 8 + slot)
                           : (256 + ((slot - 8) >> 3) * 256 + w * 8 + ((slot - 8) & 7));
#pragma unroll
      for (int r = 0; r < 4; ++r) {
        int b = mt * 16 + fq * 4 + r;
        st_f32_sys(&Y1[b * 1024 + col], acc[r]);
      }
    }
    target += WPG; group_barrier(cnt, target);

    // ---------------- phase 2: attention for b = w
    {
      const __half* pi_row = Pp + ((size_t)p * BATCH + bg_att) * 256;
      uint2 piu = *(const uint2*)(pi_row + h0);
      float2 pa = __half22float2(__builtin_bit_cast(__half2, piu.x));
      float2 pb = __half22float2(__builtin_bit_cast(__half2, piu.y));
      float4 lh4 = ldx4_sys(&Y1[w * 1024 + h0]);
      float c0 = pa.x + lh4.x, c1 = pa.y + lh4.y, c2 = pb.x + lh4.z, c3 = pb.y + lh4.w;
      for (int q = wave; q < Q_LEN; q += 4) {
        uint2 qu = *(const uint2*)(Qp + ((size_t)q * BATCH + bg_att) * 256 + h0);
        float2 qa = __half22float2(__builtin_bit_cast(__half2, qu.x));
        float2 qb = __half22float2(__builtin_bit_cast(__half2, qu.y));
        float s = vt0 * fast_tanh(qa.x + c0) + vt1 * fast_tanh(qa.y + c1) +
                  vt2 * fast_tanh(qb.x + c2) + vt3 * fast_tanh(qb.y + c3);
        s += __shfl_xor(s, 1);
        s += __shfl_xor(s, 2);
        s += __shfl_xor(s, 4);
        s += __shfl_xor(s, 8);
        s += __shfl_xor(s, 16);
        s += __shfl_xor(s, 32);
        if (lane == 0) s_logits[q] = s;
      }
      __syncthreads();
      if (wave == 0) {  // softmax over q
        float x0 = s_logits[lane];
        float x1 = (lane < Q_LEN - 64) ? s_logits[lane + 64] : -1e30f;
        float m = fmaxf(x0, x1);
        m = fmaxf(m, __shfl_xor(m, 1));
        m = fmaxf(m, __shfl_xor(m, 2));
        m = fmaxf(m, __shfl_xor(m, 4));
        m = fmaxf(m, __shfl_xor(m, 8));
        m = fmaxf(m, __shfl_xor(m, 16));
        m = fmaxf(m, __shfl_xor(m, 32));
        float e0 = fexp2((x0 - m) * LOG2E);
        float e1 = (lane < Q_LEN - 64) ? fexp2((x1 - m) * LOG2E) : 0.0f;
        float ssum = e0 + e1;
        ssum += __shfl_xor(ssum, 1);
        ssum += __shfl_xor(ssum, 2);
        ssum += __shfl_xor(ssum, 4);
        ssum += __shfl_xor(ssum, 8);
        ssum += __shfl_xor(ssum, 16);
        ssum += __shfl_xor(ssum, 32);
        float inv = 1.0f / ssum;
        s_a[lane] = e0 * inv;
        if (lane < Q_LEN - 64) s_a[lane + 64] = e1 * inv;
      }
      __syncthreads();
      // ct partials: each wave sums its q's
      float a0 = 0.f, a1 = 0.f, a2 = 0.f, a3 = 0.f;
      for (int q = wave; q < Q_LEN; q += 4) {
        float aq = s_a[q];
        uint2 qu = *(const uint2*)(Qp + ((size_t)q * BATCH + bg_att) * 256 + h0);
        float2 qa = __half22float2(__builtin_bit_cast(__half2, qu.x));
        float2 qb = __half22float2(__builtin_bit_cast(__half2, qu.y));
        a0 = fmaf(aq, qa.x, a0);
        a1 = fmaf(aq, qa.y, a1);
        a2 = fmaf(aq, qb.x, a2);
        a3 = fmaf(aq, qb.y, a3);
      }
      *(float4*)&scratch[wave * 256 + h0] = make_float4(a0, a1, a2, a3);
      __syncthreads();
      if (t < 128) {
        // p_i half of utct: elements 2t, 2t+1 (bit-identical to f16 roundtrip)
        int j2 = t * 2;
        unsigned pu = *(const unsigned*)(pi_row + j2);
        float2 pf = __half22float2(__builtin_bit_cast(__half2, pu));
        f32x2 uf2 = {pf.x, pf.y};
        st2f_sys(&uF[w * 512 + j2], uf2);
        st_u32_sys((unsigned*)&uH[w * 512 + j2], pu);
      } else {
        // ct half of utct
        int j2 = (t - 128) * 2;
        float cc0 = scratch[j2] + scratch[256 + j2] + scratch[512 + j2] + scratch[768 + j2];
        float cc1 = scratch[j2 + 1] + scratch[256 + j2 + 1] + scratch[512 + j2 + 1] +
                    scratch[768 + j2 + 1];
        f32x2 uf2 = {cc0, cc1};
        st2f_sys(&uF[w * 512 + 256 + j2], uf2);
        __half2 h2 = __floats2half2_rn(cc0, cc1);
        st_u32_sys((unsigned*)&uH[w * 512 + 256 + j2], __builtin_bit_cast(unsigned, h2));
      }
    }
    target += WPG; group_barrier(cnt, target);

    // ---------------- GEMM2: gv = Wg@utct; x = utct * sigmoid(gv)  (M=32,N=16,K=512)
    if (wave < 2) {
      const int mt = wave;
      const __half* arow = uH + (mt * 16 + fr) * 512 + fk;
      f16x8 af[16];
      ld16h_sys(arow, af[0], af[1], af[2], af[3], af[4], af[5], af[6], af[7],
                af[8], af[9], af[10], af[11], af[12], af[13], af[14], af[15]);
      f32x4 acc = {0.f, 0.f, 0.f, 0.f};
#pragma unroll
      for (int kc = 0; kc < 16; ++kc) {
        f16x8 bf = *(const f16x8*)&sWg[fr][kc * 32 + fk];
        acc = __builtin_amdgcn_mfma_f32_16x16x32_f16(af[kc], bf, acc, 0, 0, 0);
      }
      int j = w * 16 + fr;
      int b0 = mt * 16 + fq * 4;
      float4 ufv = ld4f_sys(&uF[b0 * 512 + j], &uF[(b0 + 1) * 512 + j],
                            &uF[(b0 + 2) * 512 + j], &uF[(b0 + 3) * 512 + j]);
      st_h16_sys(&xH[b0 * 512 + j],       __float2half(ufv.x * fast_sigmoid(acc[0])));
      st_h16_sys(&xH[(b0 + 1) * 512 + j], __float2half(ufv.y * fast_sigmoid(acc[1])));
      st_h16_sys(&xH[(b0 + 2) * 512 + j], __float2half(ufv.z * fast_sigmoid(acc[2])));
      st_h16_sys(&xH[(b0 + 3) * 512 + j], __float2half(ufv.w * fast_sigmoid(acc[3])));
    }
    target += WPG; group_barrier(cnt, target);

    // ---------------- GEMM3: xg = Wih@x (M=32,N=24,K=512) + GRU combine
    {
      const int mt = wave >> 1, nt = wave & 1;
      const __half* arow = xH + (mt * 16 + fr) * 512 + fk;
      f16x8 af[16];
      ld16h_sys(arow, af[0], af[1], af[2], af[3], af[4], af[5], af[6], af[7],
                af[8], af[9], af[10], af[11], af[12], af[13], af[14], af[15]);
      int slot = nt * 16 + fr;
      int srow = slot < 24 ? slot : 23;  // clamp pad slots (outputs unused)
      f32x4 acc = {0.f, 0.f, 0.f, 0.f};
#pragma unroll
      for (int kc = 0; kc < 16; ++kc) {
        f16x8 bf = *(const f16x8*)&sW3[srow][kc * 32 + fk];
        acc = __builtin_amdgcn_mfma_f32_16x16x32_f16(af[kc], bf, acc, 0, 0, 0);
      }
      if (slot < 24) {
#pragma unroll
        for (int r = 0; r < 4; ++r) {
          int b = mt * 16 + fq * 4 + r;
          scratch[b * 24 + slot] = acc[r];
        }
      }
      __syncthreads();
      {
        int b = t >> 3, jl = t & 7;
        int jj = w * 8 + jl;
        float xr = scratch[b * 24 + jl];
        float xz = scratch[b * 24 + 8 + jl];
        float xn = scratch[b * 24 + 16 + jl];
        float4 yv = ld4f_sys(&Y1[b * 1024 + 256 + jj], &Y1[b * 1024 + 512 + jj],
                             &Y1[b * 1024 + 768 + jj], &pF[b * 256 + jj]);
        float r = fast_sigmoid(xr + yv.x);
        float z = fast_sigmoid(xz + yv.y);
        float n = fast_tanh(xn + r * yv.z);
        float h = (1.0f - z) * n + z * yv.w;
        int bgl = g * BPG + b;
        out[((size_t)p * BATCH + bgl) * 256 + jj] = h;  // write-once: normal store
        st_f32_sys(&pF[b * 256 + jj], h);
        st_h16_sys(&pH[b * 256 + jj], __float2half(h));
      }
    }
    target += WPG; group_barrier(cnt, target);
  }
}

// ---------------------------------------------------------------- launch
extern "C" void kernel_launch(void* const* d_in, const int* in_sizes, int n_in,
                              void* d_out, int out_size, void* d_ws, size_t ws_size,
                              hipStream_t stream) {
  const float* passage  = (const float*)d_in[0];
  const float* question = (const float*)d_in[1];
  const float* vT  = (const float*)d_in[4];
  const float* WuQ = (const float*)d_in[5];
  const float* WuP = (const float*)d_in[6];
  const float* WvP = (const float*)d_in[7];
  const float* Wg  = (const float*)d_in[8];
  const float* Wih = (const float*)d_in[9];
  const float* Whh = (const float*)d_in[10];
  float* out = (float*)d_out;

  char* base = (char*)d_ws;
  size_t off = 0;
  auto alloc = [&](size_t bytes) {
    char* p = base + off;
    off = (off + bytes + 255) & ~(size_t)255;
    return p;
  };
  __half* Pp16  = (__half*)alloc((size_t)P_LEN * BATCH * HID * 2);
  __half* Qp16  = (__half*)alloc((size_t)Q_LEN * BATCH * HID * 2);
  __half* WuQ16 = (__half*)alloc((size_t)HID * D_IN * 2);
  __half* WuP16 = (__half*)alloc((size_t)HID * D_IN * 2);
  __half* WvP16 = (__half*)alloc((size_t)HID * HID * 2);
  __half* Wg16  = (__half*)alloc((size_t)2 * HID * 2 * HID * 2);
  __half* Wih16 = (__half*)alloc((size_t)3 * HID * 2 * HID * 2);
  __half* Whh16 = (__half*)alloc((size_t)3 * HID * HID * 2);
  float*  Y1b   = (float*)alloc((size_t)NGROUP * BPG * 1024 * 4);
  float*  uFb   = (float*)alloc((size_t)NGROUP * BPG * 512 * 4);
  __half* uHb   = (__half*)alloc((size_t)NGROUP * BPG * 512 * 2);
  __half* xHb   = (__half*)alloc((size_t)NGROUP * BPG * 512 * 2);
  // zero-region: prev f32, prev f16, barrier counters (contiguous)
  char* zbase = base + off;
  float*  pFb   = (float*)alloc((size_t)NGROUP * BPG * 256 * 4);
  __half* pHb   = (__half*)alloc((size_t)NGROUP * BPG * 256 * 2);
  unsigned* bars = (unsigned*)alloc((size_t)NGROUP * 64 * 4);
  size_t zbytes = (base + off) - zbase;

  hipMemsetAsync(zbase, 0, zbytes, stream);

  cvt_f32_f16<<<64, 256, 0, stream>>>(WuQ, WuQ16, HID * D_IN);
  cvt_f32_f16<<<64, 256, 0, stream>>>(WuP, WuP16, HID * D_IN);
  cvt_f32_f16<<<32, 256, 0, stream>>>(WvP, WvP16, HID * HID);
  cvt_f32_f16<<<64, 256, 0, stream>>>(Wg, Wg16, 2 * HID * 2 * HID);
  cvt_f32_f16<<<64, 256, 0, stream>>>(Wih, Wih16, 3 * HID * 2 * HID);
  cvt_f32_f16<<<64, 256, 0, stream>>>(Whh, Whh16, 3 * HID * HID);

  gemm_a32w16<<<dim3(Q_LEN * BATCH / BM, HID / BN), 256, 0, stream>>>(
      question, WuQ16, Qp16, Q_LEN * BATCH, HID, D_IN);
  gemm_a32w16<<<dim3(P_LEN * BATCH / BM, HID / BN), 256, 0, stream>>>(
      passage, WuP16, Pp16, P_LEN * BATCH, HID, D_IN);

  scan_coop<<<NGROUP * WPG, NTHR, 0, stream>>>(
      Pp16, Qp16, WvP16, Whh16, Wg16, Wih16, vT, out,
      Y1b, uFb, uHb, xHb, pFb, pHb, bars);
}

// Round 2
// 27224.460 us; speedup vs baseline: 1.8855x; 1.0358x over previous
//
#include <hip/hip_runtime.h>
#include <hip/hip_fp16.h>

#define P_LEN 1000
#define Q_LEN 100
#define BATCH 128
#define D_IN 512
#define HID 256

#define NGROUP 4
#define WPG 32   // workgroups per group
#define BPG 32   // batches per group
#define NTHR 256

typedef _Float16 f16x8 __attribute__((ext_vector_type(8)));
typedef float f32x4 __attribute__((ext_vector_type(4)));
typedef float f32x2 __attribute__((ext_vector_type(2)));

#define LOG2E 1.4426950408889634f

__device__ __forceinline__ float fexp2(float x) {
#if __has_builtin(__builtin_amdgcn_exp2f)
  return __builtin_amdgcn_exp2f(x);
#else
  return exp2f(x);
#endif
}
__device__ __forceinline__ float frcp(float x) {
#if __has_builtin(__builtin_amdgcn_rcpf)
  return __builtin_amdgcn_rcpf(x);
#else
  return 1.0f / x;
#endif
}
__device__ __forceinline__ float fast_tanh(float x) {
  float t = fexp2(x * (2.0f * LOG2E));
  return (t - 1.0f) * frcp(t + 1.0f);
}
__device__ __forceinline__ float fast_sigmoid(float x) {
  return frcp(1.0f + fexp2(-x * LOG2E));
}

// ---------------------------------------------------------------- coherent (LLC) access
// Cross-WG exchange bypasses L1/L2 (sc0 sc1), serviced at the Infinity Cache
// (device coherence point). No cache writeback/invalidate anywhere.

__device__ __forceinline__ void st_f32_sys(float* p, float v) {
  asm volatile("global_store_dword %0, %1, off sc0 sc1" :: "v"(p), "v"(v) : "memory");
}
__device__ __forceinline__ void st2f_sys(float* p, f32x2 v) {
  asm volatile("global_store_dwordx2 %0, %1, off sc0 sc1" :: "v"(p), "v"(v) : "memory");
}
__device__ __forceinline__ void st_u32_sys(unsigned* p, unsigned v) {
  asm volatile("global_store_dword %0, %1, off sc0 sc1" :: "v"(p), "v"(v) : "memory");
}
__device__ __forceinline__ void st_h16_sys(__half* p, __half v) {
  unsigned u = (unsigned)__half_as_ushort(v);
  asm volatile("global_store_short %0, %1, off sc0 sc1" :: "v"(p), "v"(u) : "memory");
}

__device__ __forceinline__ float4 ldx4_sys(const float* p) {
  f32x4 v;
  asm volatile("global_load_dwordx4 %0, %1, off sc0 sc1\n\t"
               "s_waitcnt vmcnt(0)"
               : "=&v"(v) : "v"(p) : "memory");
  return make_float4(v.x, v.y, v.z, v.w);
}

// issue-only loads (no waitcnt): consumed after a later vmcnt(0) (barrier drain)
__device__ __forceinline__ void ld3f_issue(const float* p0, const float* p1, const float* p2,
                                           float& a, float& b, float& c) {
  asm volatile(
      "global_load_dword %0, %3, off sc0 sc1\n\t"
      "global_load_dword %1, %4, off sc0 sc1\n\t"
      "global_load_dword %2, %5, off sc0 sc1"
      : "=&v"(a), "=&v"(b), "=&v"(c)
      : "v"(p0), "v"(p1), "v"(p2)
      : "memory");
}
__device__ __forceinline__ void ld4f_issue(const float* p0, const float* p1,
                                           const float* p2, const float* p3,
                                           float& a, float& b, float& c, float& d) {
  asm volatile(
      "global_load_dword %0, %4, off sc0 sc1\n\t"
      "global_load_dword %1, %5, off sc0 sc1\n\t"
      "global_load_dword %2, %6, off sc0 sc1\n\t"
      "global_load_dword %3, %7, off sc0 sc1"
      : "=&v"(a), "=&v"(b), "=&v"(c), "=&v"(d)
      : "v"(p0), "v"(p1), "v"(p2), "v"(p3)
      : "memory");
}

// 8 x 16B from one row (stride 64B), single LLC latency.
__device__ __forceinline__ void ld8h_sys(const __half* p,
    f16x8& o0, f16x8& o1, f16x8& o2, f16x8& o3,
    f16x8& o4, f16x8& o5, f16x8& o6, f16x8& o7) {
  asm volatile(
      "global_load_dwordx4 %0, %8, off sc0 sc1\n\t"
      "global_load_dwordx4 %1, %8, off offset:64 sc0 sc1\n\t"
      "global_load_dwordx4 %2, %8, off offset:128 sc0 sc1\n\t"
      "global_load_dwordx4 %3, %8, off offset:192 sc0 sc1\n\t"
      "global_load_dwordx4 %4, %8, off offset:256 sc0 sc1\n\t"
      "global_load_dwordx4 %5, %8, off offset:320 sc0 sc1\n\t"
      "global_load_dwordx4 %6, %8, off offset:384 sc0 sc1\n\t"
      "global_load_dwordx4 %7, %8, off offset:448 sc0 sc1\n\t"
      "s_waitcnt vmcnt(0)"
      : "=&v"(o0), "=&v"(o1), "=&v"(o2), "=&v"(o3),
        "=&v"(o4), "=&v"(o5), "=&v"(o6), "=&v"(o7)
      : "v"(p)
      : "memory");
}

// 16 x 16B from one row (stride 64B), single LLC latency.
__device__ __forceinline__ void ld16h_sys(const __half* p,
    f16x8& o0, f16x8& o1, f16x8& o2, f16x8& o3,
    f16x8& o4, f16x8& o5, f16x8& o6, f16x8& o7,
    f16x8& o8, f16x8& o9, f16x8& o10, f16x8& o11,
    f16x8& o12, f16x8& o13, f16x8& o14, f16x8& o15) {
  asm volatile(
      "global_load_dwordx4 %0, %16, off sc0 sc1\n\t"
      "global_load_dwordx4 %1, %16, off offset:64 sc0 sc1\n\t"
      "global_load_dwordx4 %2, %16, off offset:128 sc0 sc1\n\t"
      "global_load_dwordx4 %3, %16, off offset:192 sc0 sc1\n\t"
      "global_load_dwordx4 %4, %16, off offset:256 sc0 sc1\n\t"
      "global_load_dwordx4 %5, %16, off offset:320 sc0 sc1\n\t"
      "global_load_dwordx4 %6, %16, off offset:384 sc0 sc1\n\t"
      "global_load_dwordx4 %7, %16, off offset:448 sc0 sc1\n\t"
      "global_load_dwordx4 %8, %16, off offset:512 sc0 sc1\n\t"
      "global_load_dwordx4 %9, %16, off offset:576 sc0 sc1\n\t"
      "global_load_dwordx4 %10, %16, off offset:640 sc0 sc1\n\t"
      "global_load_dwordx4 %11, %16, off offset:704 sc0 sc1\n\t"
      "global_load_dwordx4 %12, %16, off offset:768 sc0 sc1\n\t"
      "global_load_dwordx4 %13, %16, off offset:832 sc0 sc1\n\t"
      "global_load_dwordx4 %14, %16, off offset:896 sc0 sc1\n\t"
      "global_load_dwordx4 %15, %16, off offset:960 sc0 sc1\n\t"
      "s_waitcnt vmcnt(0)"
      : "=&v"(o0), "=&v"(o1), "=&v"(o2), "=&v"(o3),
        "=&v"(o4), "=&v"(o5), "=&v"(o6), "=&v"(o7),
        "=&v"(o8), "=&v"(o9), "=&v"(o10), "=&v"(o11),
        "=&v"(o12), "=&v"(o13), "=&v"(o14), "=&v"(o15)
      : "v"(p)
      : "memory");
}

// ---------------------------------------------------------------- convert
__global__ void cvt_f32_f16(const float* __restrict__ src, __half* __restrict__ dst, int n) {
  int i = blockIdx.x * blockDim.x + threadIdx.x;
  int stride = gridDim.x * blockDim.x;
  for (; i < n; i += stride) dst[i] = __float2half(src[i]);
}

// ---------------------------------------------------------------- GEMM (precompute Qp/Pp)
#define BM 128
#define BN 64
#define BK 32
__global__ __launch_bounds__(256) void gemm_a32w16(const float* __restrict__ A,
                                                   const __half* __restrict__ W,
                                                   __half* __restrict__ C,
                                                   int M, int N, int K) {
  __shared__ __align__(16) __half As[BM][BK + 8];
  __shared__ __align__(16) __half Bs[BN][BK + 8];
  int t = threadIdx.x;
  int lane = t & 63, wave = t >> 6;
  int wm = wave >> 1, wn = wave & 1;
  int bm = blockIdx.x * BM, bn = blockIdx.y * BN;
  f32x4 acc[4][2] = {};
  int fr = lane & 15, fk = (lane >> 4) * 8, fq = lane >> 4;

  for (int kk = 0; kk < K; kk += BK) {
    {
      int r = t >> 1, c0 = (t & 1) * 16;
      const float* ap = A + (long)(bm + r) * K + kk + c0;
      float4 f0 = ((const float4*)ap)[0];
      float4 f1 = ((const float4*)ap)[1];
      float4 f2 = ((const float4*)ap)[2];
      float4 f3 = ((const float4*)ap)[3];
      __half2* dp = (__half2*)&As[r][c0];
      dp[0] = __float22half2_rn(make_float2(f0.x, f0.y));
      dp[1] = __float22half2_rn(make_float2(f0.z, f0.w));
      dp[2] = __float22half2_rn(make_float2(f1.x, f1.y));
      dp[3] = __float22half2_rn(make_float2(f1.z, f1.w));
      dp[4] = __float22half2_rn(make_float2(f2.x, f2.y));
      dp[5] = __float22half2_rn(make_float2(f2.z, f2.w));
      dp[6] = __float22half2_rn(make_float2(f3.x, f3.y));
      dp[7] = __float22half2_rn(make_float2(f3.z, f3.w));
    }
    {
      int r = t >> 2, c0 = (t & 3) * 8;
      uint4 w = *(const uint4*)(W + (long)(bn + r) * K + kk + c0);
      *(uint4*)&Bs[r][c0] = w;
    }
    __syncthreads();
    f16x8 af[4], bf[2];
#pragma unroll
    for (int i = 0; i < 4; i++) af[i] = *(const f16x8*)&As[wm * 64 + i * 16 + fr][fk];
#pragma unroll
    for (int j = 0; j < 2; j++) bf[j] = *(const f16x8*)&Bs[wn * 32 + j * 16 + fr][fk];
#pragma unroll
    for (int i = 0; i < 4; i++)
#pragma unroll
      for (int j = 0; j < 2; j++)
        acc[i][j] = __builtin_amdgcn_mfma_f32_16x16x32_f16(af[i], bf[j], acc[i][j], 0, 0, 0);
    __syncthreads();
  }
#pragma unroll
  for (int i = 0; i < 4; i++)
#pragma unroll
    for (int j = 0; j < 2; j++)
#pragma unroll
      for (int r = 0; r < 4; r++) {
        int row = bm + wm * 64 + i * 16 + fq * 4 + r;
        int col = bn + wn * 32 + j * 16 + fr;
        C[(long)row * N + col] = __float2half(acc[i][j][r]);
      }
}

// ---------------------------------------------------------------- group barrier
// Store+poll: no RMW serialization. Each WG stores a monotone phase counter to
// its own slot (sc0 sc1, after vmcnt drain = release). Wave 0 polls all 32
// slots with one coalesced load per iteration; __all detects arrival.
__device__ __forceinline__ void group_barrier(unsigned* flags, int w, unsigned ph) {
  asm volatile("s_waitcnt vmcnt(0)" ::: "memory");
  __syncthreads();
  int t = threadIdx.x;
  if (t < 64) {
    if (t == 0) {
      asm volatile("global_store_dword %0, %1, off sc0 sc1"
                   :: "v"(flags + w), "v"(ph) : "memory");
    }
    const unsigned* slot = flags + (t & 31);
    unsigned v;
    do {
      asm volatile("global_load_dword %0, %1, off sc0 sc1\n\ts_waitcnt vmcnt(0)"
                   : "=&v"(v) : "v"(slot) : "memory");
    } while (!__all((int)(v >= ph)));
  }
  __syncthreads();
}

// ---------------------------------------------------------------- cooperative scan
__global__ __launch_bounds__(256) void scan_coop(
    const __half* __restrict__ Pp, const __half* __restrict__ Qp,
    const __half* __restrict__ WvP, const __half* __restrict__ Whh,
    const __half* __restrict__ Wg, const __half* __restrict__ Wih,
    const float* __restrict__ vT, float* __restrict__ out,
    float* __restrict__ Y1b,   // [G][32][1024] f32: cols 0..255 lh, 256.. hh(r,z,n)
    float* __restrict__ uFb,   // [G][32][512]  f32 utct
    __half* __restrict__ uHb,  // [G][32][512]  f16 utct
    __half* __restrict__ xHb,  // [G][32][512]  f16 x
    __half* __restrict__ pHb,  // [G][32][256]  f16 prev
    unsigned* __restrict__ bars)  // [G][64] flag slots (256B/group)
{
  const int bid = blockIdx.x;
  const int g = bid >> 5;
  const int w = bid & 31;
  const int t = threadIdx.x;
  const int lane = t & 63, wave = t >> 6;
  const int fr = lane & 15, fq = lane >> 4;
  const int fk = fq * 8;

  float* Y1 = Y1b + (size_t)g * BPG * 1024;
  float* uF = uFb + (size_t)g * BPG * 512;
  __half* uH = uHb + (size_t)g * BPG * 512;
  __half* xH = xHb + (size_t)g * BPG * 512;
  __half* pH = pHb + (size_t)g * BPG * 256;
  unsigned* flags = bars + g * 64;

  // Weight tiles, XOR-swizzled in 16B chunks: chunk' = chunk ^ (row & 7).
  // Row strides are multiples of 128B, so without swizzle all fr-lanes of an
  // MFMA B-fragment read hit the same bank group (16-way conflict).
  __shared__ __align__(16) __half sW1[32][256];   // slots: 0..7 WvP rows w*8+s; 8..31 Whh gate rows
  __shared__ __align__(16) __half sWg[16][512];   // Wg rows w*16+s
  __shared__ __align__(16) __half sW3[24][512];   // Wih gate rows (8 per gate at jj=w*8..)
  __shared__ __align__(16) float scratch[1024];   // phase2 ct partials / gemm3 xg staging
  __shared__ float s_logits[Q_LEN];
  __shared__ float s_a[Q_LEN];

  // ---- load resident weight slices (normal cached loads; read-once)
  for (int i = t; i < 32 * 32; i += NTHR) {       // sW1: 32 slots x 32 chunks
    int slot = i >> 5, c = i & 31;
    const __half* src;
    if (slot < 8) src = WvP + (size_t)(w * 8 + slot) * 256;
    else {
      int gate = (slot - 8) >> 3, jl = (slot - 8) & 7;
      src = Whh + (size_t)(gate * 256 + w * 8 + jl) * 256;
    }
    int cs = c ^ (slot & 7);
    *(uint4*)&sW1[slot][cs * 8] = *(const uint4*)(src + c * 8);
  }
  for (int i = t; i < 16 * 64; i += NTHR) {       // sWg
    int s = i >> 6, c = i & 63;
    int cs = c ^ (s & 7);
    *(uint4*)&sWg[s][cs * 8] = *(const uint4*)(Wg + (size_t)(w * 16 + s) * 512 + c * 8);
  }
  for (int i = t; i < 24 * 64; i += NTHR) {       // sW3
    int s = i >> 6, c = i & 63;
    int gate = s >> 3, jl = s & 7;
    int cs = c ^ (s & 7);
    *(uint4*)&sW3[s][cs * 8] =
        *(const uint4*)(Wih + (size_t)(gate * 256 + w * 8 + jl) * 512 + c * 8);
  }

  const int bg_att = g * BPG + w;   // this WG's batch for the attention phase
  const int h0 = lane * 4;
  float vt0 = vT[h0], vt1 = vT[h0 + 1], vt2 = vT[h0 + 2], vt3 = vT[h0 + 3];

  // GRU combine mapping for this thread (persistent across phases)
  const int bb_ = t >> 3, jl_ = t & 7;
  const int jjg_ = w * 8 + jl_;
  float pv_ = 0.0f;                 // prev[bb_][jjg_] lives in a register

  __syncthreads();

  unsigned ph = 0;

  for (int p = 0; p < P_LEN; ++p) {
    float hr_, hz_, hn_;            // GRU hh-gate operands, prefetched in phase 2

    // ---------------- GEMM1: Y1[b][col] = [WvP;Whh] @ prev   (M=32,N=32,K=256)
    {
      const int mt = wave >> 1, nt = wave & 1;
      const __half* arow = pH + (mt * 16 + fr) * 256 + fk;
      f16x8 af[8];
      ld8h_sys(arow, af[0], af[1], af[2], af[3], af[4], af[5], af[6], af[7]);
      f32x4 acc = {0.f, 0.f, 0.f, 0.f};
#pragma unroll
      for (int kc = 0; kc < 8; ++kc) {
        int ch = ((kc * 4 + fq) ^ (fr & 7)) * 8;
        f16x8 bf = *(const f16x8*)&sW1[nt * 16 + fr][ch];
        acc = __builtin_amdgcn_mfma_f32_16x16x32_f16(af[kc], bf, acc, 0, 0, 0);
      }
      int slot = nt * 16 + fr;
      int col = (slot < 8) ? (w * 8 + slot)
                           : (256 + ((slot - 8) >> 3) * 256 + w * 8 + ((slot - 8) & 7));
#pragma unroll
      for (int r = 0; r < 4; ++r) {
        int b = mt * 16 + fq * 4 + r;
        st_f32_sys(&Y1[b * 1024 + col], acc[r]);
      }
    }
    ++ph; group_barrier(flags, w, ph);

    // ---------------- phase 2: attention for b = w
    {
      const __half* pi_row = Pp + ((size_t)p * BATCH + bg_att) * 256;
      uint2 piu = *(const uint2*)(pi_row + h0);
      float2 pa = __half22float2(__builtin_bit_cast(__half2, piu.x));
      float2 pb = __half22float2(__builtin_bit_cast(__half2, piu.y));
      float4 lh4 = ldx4_sys(&Y1[w * 1024 + h0]);
      // prefetch GRU hh-gate operands (consumed in phase 4, after 2 vmcnt drains)
      ld3f_issue(&Y1[bb_ * 1024 + 256 + jjg_], &Y1[bb_ * 1024 + 512 + jjg_],
                 &Y1[bb_ * 1024 + 768 + jjg_], hr_, hz_, hn_);
      float c0 = pa.x + lh4.x, c1 = pa.y + lh4.y, c2 = pb.x + lh4.z, c3 = pb.y + lh4.w;
      for (int q = wave; q < Q_LEN; q += 4) {
        uint2 qu = *(const uint2*)(Qp + ((size_t)q * BATCH + bg_att) * 256 + h0);
        float2 qa = __half22float2(__builtin_bit_cast(__half2, qu.x));
        float2 qb = __half22float2(__builtin_bit_cast(__half2, qu.y));
        float s = vt0 * fast_tanh(qa.x + c0) + vt1 * fast_tanh(qa.y + c1) +
                  vt2 * fast_tanh(qb.x + c2) + vt3 * fast_tanh(qb.y + c3);
        s += __shfl_xor(s, 1);
        s += __shfl_xor(s, 2);
        s += __shfl_xor(s, 4);
        s += __shfl_xor(s, 8);
        s += __shfl_xor(s, 16);
        s += __shfl_xor(s, 32);
        if (lane == 0) s_logits[q] = s;
      }
      __syncthreads();
      if (wave == 0) {  // softmax over q
        float x0 = s_logits[lane];
        float x1 = (lane < Q_LEN - 64) ? s_logits[lane + 64] : -1e30f;
        float m = fmaxf(x0, x1);
        m = fmaxf(m, __shfl_xor(m, 1));
        m = fmaxf(m, __shfl_xor(m, 2));
        m = fmaxf(m, __shfl_xor(m, 4));
        m = fmaxf(m, __shfl_xor(m, 8));
        m = fmaxf(m, __shfl_xor(m, 16));
        m = fmaxf(m, __shfl_xor(m, 32));
        float e0 = fexp2((x0 - m) * LOG2E);
        float e1 = (lane < Q_LEN - 64) ? fexp2((x1 - m) * LOG2E) : 0.0f;
        float ssum = e0 + e1;
        ssum += __shfl_xor(ssum, 1);
        ssum += __shfl_xor(ssum, 2);
        ssum += __shfl_xor(ssum, 4);
        ssum += __shfl_xor(ssum, 8);
        ssum += __shfl_xor(ssum, 16);
        ssum += __shfl_xor(ssum, 32);
        float inv = 1.0f / ssum;
        s_a[lane] = e0 * inv;
        if (lane < Q_LEN - 64) s_a[lane + 64] = e1 * inv;
      }
      __syncthreads();
      // ct partials: each wave sums its q's
      float a0 = 0.f, a1 = 0.f, a2 = 0.f, a3 = 0.f;
      for (int q = wave; q < Q_LEN; q += 4) {
        float aq = s_a[q];
        uint2 qu = *(const uint2*)(Qp + ((size_t)q * BATCH + bg_att) * 256 + h0);
        float2 qa = __half22float2(__builtin_bit_cast(__half2, qu.x));
        float2 qb = __half22float2(__builtin_bit_cast(__half2, qu.y));
        a0 = fmaf(aq, qa.x, a0);
        a1 = fmaf(aq, qa.y, a1);
        a2 = fmaf(aq, qb.x, a2);
        a3 = fmaf(aq, qb.y, a3);
      }
      *(float4*)&scratch[wave * 256 + h0] = make_float4(a0, a1, a2, a3);
      __syncthreads();
      if (t < 128) {
        // p_i half of utct: elements 2t, 2t+1 (bit-identical to f16 roundtrip)
        int j2 = t * 2;
        unsigned pu = *(const unsigned*)(pi_row + j2);
        float2 pf = __half22float2(__builtin_bit_cast(__half2, pu));
        f32x2 uf2 = {pf.x, pf.y};
        st2f_sys(&uF[w * 512 + j2], uf2);
        st_u32_sys((unsigned*)&uH[w * 512 + j2], pu);
      } else {
        // ct half of utct
        int j2 = (t - 128) * 2;
        float cc0 = scratch[j2] + scratch[256 + j2] + scratch[512 + j2] + scratch[768 + j2];
        float cc1 = scratch[j2 + 1] + scratch[256 + j2 + 1] + scratch[512 + j2 + 1] +
                    scratch[768 + j2 + 1];
        f32x2 uf2 = {cc0, cc1};
        st2f_sys(&uF[w * 512 + 256 + j2], uf2);
        __half2 h2 = __floats2half2_rn(cc0, cc1);
        st_u32_sys((unsigned*)&uH[w * 512 + 256 + j2], __builtin_bit_cast(unsigned, h2));
      }
    }
    ++ph; group_barrier(flags, w, ph);

    // ---------------- GEMM2: gv = Wg@utct; x = utct * sigmoid(gv)  (M=32,N=16,K=512)
    if (wave < 2) {
      const int mt = wave;
      int j = w * 16 + fr;
      int b0 = mt * 16 + fq * 4;
      float u0, u1, u2, u3;
      ld4f_issue(&uF[b0 * 512 + j], &uF[(b0 + 1) * 512 + j],
                 &uF[(b0 + 2) * 512 + j], &uF[(b0 + 3) * 512 + j], u0, u1, u2, u3);
      const __half* arow = uH + (mt * 16 + fr) * 512 + fk;
      f16x8 af[16];
      ld16h_sys(arow, af[0], af[1], af[2], af[3], af[4], af[5], af[6], af[7],
                af[8], af[9], af[10], af[11], af[12], af[13], af[14], af[15]);
      f32x4 acc = {0.f, 0.f, 0.f, 0.f};
#pragma unroll
      for (int kc = 0; kc < 16; ++kc) {
        int ch = ((kc * 4 + fq) ^ (fr & 7)) * 8;
        f16x8 bf = *(const f16x8*)&sWg[fr][ch];
        acc = __builtin_amdgcn_mfma_f32_16x16x32_f16(af[kc], bf, acc, 0, 0, 0);
      }
      st_h16_sys(&xH[b0 * 512 + j],       __float2half(u0 * fast_sigmoid(acc[0])));
      st_h16_sys(&xH[(b0 + 1) * 512 + j], __float2half(u1 * fast_sigmoid(acc[1])));
      st_h16_sys(&xH[(b0 + 2) * 512 + j], __float2half(u2 * fast_sigmoid(acc[2])));
      st_h16_sys(&xH[(b0 + 3) * 512 + j], __float2half(u3 * fast_sigmoid(acc[3])));
    }
    ++ph; group_barrier(flags, w, ph);

    // ---------------- GEMM3: xg = Wih@x (M=32,N=24,K=512) + GRU combine
    {
      const int mt = wave >> 1, nt = wave & 1;
      const __half* arow = xH + (mt * 16 + fr) * 512 + fk;
      f16x8 af[16];
      ld16h_sys(arow, af[0], af[1], af[2], af[3], af[4], af[5], af[6], af[7],
                af[8], af[9], af[10], af[11], af[12], af[13], af[14], af[15]);
      int slot = nt * 16 + fr;
      int srow = slot < 24 ? slot : 23;  // clamp pad slots (outputs unused)
      f32x4 acc = {0.f, 0.f, 0.f, 0.f};
#pragma unroll
      for (int kc = 0; kc < 16; ++kc) {
        int ch = ((kc * 4 + fq) ^ (srow & 7)) * 8;
        f16x8 bf = *(const f16x8*)&sW3[srow][ch];
        acc = __builtin_amdgcn_mfma_f32_16x16x32_f16(af[kc], bf, acc, 0, 0, 0);
      }
      if (slot < 24) {
#pragma unroll
        for (int r = 0; r < 4; ++r) {
          int b = mt * 16 + fq * 4 + r;
          scratch[b * 24 + slot] = acc[r];
        }
      }
      __syncthreads();
      {
        float xr = scratch[bb_ * 24 + jl_];
        float xz = scratch[bb_ * 24 + 8 + jl_];
        float xn = scratch[bb_ * 24 + 16 + jl_];
        float r = fast_sigmoid(xr + hr_);
        float z = fast_sigmoid(xz + hz_);
        float n = fast_tanh(xn + r * hn_);
        float h = (1.0f - z) * n + z * pv_;
        pv_ = h;
        int bgl = g * BPG + bb_;
        out[((size_t)p * BATCH + bgl) * 256 + jjg_] = h;  // write-once: normal store
        st_h16_sys(&pH[bb_ * 256 + jjg_], __float2half(h));
      }
    }
    ++ph; group_barrier(flags, w, ph);
  }
}

// ---------------------------------------------------------------- launch
extern "C" void kernel_launch(void* const* d_in, const int* in_sizes, int n_in,
                              void* d_out, int out_size, void* d_ws, size_t ws_size,
                              hipStream_t stream) {
  const float* passage  = (const float*)d_in[0];
  const float* question = (const float*)d_in[1];
  const float* vT  = (const float*)d_in[4];
  const float* WuQ = (const float*)d_in[5];
  const float* WuP = (const float*)d_in[6];
  const float* WvP = (const float*)d_in[7];
  const float* Wg  = (const float*)d_in[8];
  const float* Wih = (const float*)d_in[9];
  const float* Whh = (const float*)d_in[10];
  float* out = (float*)d_out;

  char* base = (char*)d_ws;
  size_t off = 0;
  auto alloc = [&](size_t bytes) {
    char* p = base + off;
    off = (off + bytes + 255) & ~(size_t)255;
    return p;
  };
  __half* Pp16  = (__half*)alloc((size_t)P_LEN * BATCH * HID * 2);
  __half* Qp16  = (__half*)alloc((size_t)Q_LEN * BATCH * HID * 2);
  __half* WuQ16 = (__half*)alloc((size_t)HID * D_IN * 2);
  __half* WuP16 = (__half*)alloc((size_t)HID * D_IN * 2);
  __half* WvP16 = (__half*)alloc((size_t)HID * HID * 2);
  __half* Wg16  = (__half*)alloc((size_t)2 * HID * 2 * HID * 2);
  __half* Wih16 = (__half*)alloc((size_t)3 * HID * 2 * HID * 2);
  __half* Whh16 = (__half*)alloc((size_t)3 * HID * HID * 2);
  float*  Y1b   = (float*)alloc((size_t)NGROUP * BPG * 1024 * 4);
  float*  uFb   = (float*)alloc((size_t)NGROUP * BPG * 512 * 4);
  __half* uHb   = (__half*)alloc((size_t)NGROUP * BPG * 512 * 2);
  __half* xHb   = (__half*)alloc((size_t)NGROUP * BPG * 512 * 2);
  // zero-region: prev f16, barrier flag slots (contiguous)
  char* zbase = base + off;
  __half* pHb   = (__half*)alloc((size_t)NGROUP * BPG * 256 * 2);
  unsigned* bars = (unsigned*)alloc((size_t)NGROUP * 64 * 4);
  size_t zbytes = (base + off) - zbase;

  hipMemsetAsync(zbase, 0, zbytes, stream);

  cvt_f32_f16<<<64, 256, 0, stream>>>(WuQ, WuQ16, HID * D_IN);
  cvt_f32_f16<<<64, 256, 0, stream>>>(WuP, WuP16, HID * D_IN);
  cvt_f32_f16<<<32, 256, 0, stream>>>(WvP, WvP16, HID * HID);
  cvt_f32_f16<<<64, 256, 0, stream>>>(Wg, Wg16, 2 * HID * 2 * HID);
  cvt_f32_f16<<<64, 256, 0, stream>>>(Wih, Wih16, 3 * HID * 2 * HID);
  cvt_f32_f16<<<64, 256, 0, stream>>>(Whh, Whh16, 3 * HID * HID);

  gemm_a32w16<<<dim3(Q_LEN * BATCH / BM, HID / BN), 256, 0, stream>>>(
      question, WuQ16, Qp16, Q_LEN * BATCH, HID, D_IN);
  gemm_a32w16<<<dim3(P_LEN * BATCH / BM, HID / BN), 256, 0, stream>>>(
      passage, WuP16, Pp16, P_LEN * BATCH, HID, D_IN);

  scan_coop<<<NGROUP * WPG, NTHR, 0, stream>>>(
      Pp16, Qp16, WvP16, Whh16, Wg16, Wih16, vT, out,
      Y1b, uFb, uHb, xHb, pHb, bars);
}